// Round 1
// baseline (290.074 us; speedup 1.0000x reference)
//
#include <hip/hip_runtime.h>
#include <hip/hip_bf16.h>
#include <stdint.h>

typedef __attribute__((ext_vector_type(8))) short short8;
typedef __attribute__((ext_vector_type(4))) float floatx4;

__device__ __forceinline__ unsigned short f2b(float f) {
  union { float f; uint32_t u; } v; v.f = f;
  uint32_t u = v.u;
  uint32_t r = u + 0x7FFFu + ((u >> 16) & 1u);   // round-to-nearest-even
  return (unsigned short)(r >> 16);
}
__device__ __forceinline__ float b2f(unsigned short h) {
  union { uint32_t u; float f; } v; v.u = ((uint32_t)h) << 16;
  return v.f;
}

// ---- Wt[n][k] = bf16(W[k][n]) : tiny 256x256 transpose+convert ----
__global__ void wt_kernel(const float* __restrict__ W, unsigned short* __restrict__ Wt) {
  int n = blockIdx.x, k = threadIdx.x;
  Wt[n * 256 + k] = f2b(W[k * 256 + n]);
}

// ---- xwb[M,256] = bf16( x @ W ), bf16 MFMA, BM=64 BN=64 BK=32 ----
#define LDA 40   // 32 + 8 pad (80B row stride -> 16B aligned, bank-spread)
__global__ __launch_bounds__(256) void gemm_kernel(
    const float* __restrict__ x, const unsigned short* __restrict__ Wt,
    unsigned short* __restrict__ xwb, int M)
{
  __shared__ unsigned short As[64 * LDA];
  __shared__ unsigned short Bs[64 * LDA];
  const int tid  = threadIdx.x;
  const int lane = tid & 63;
  const int wave = tid >> 6;
  const int bm = blockIdx.x * 64;
  const int bn = blockIdx.y * 64;
  const int wm = (wave & 1) * 32;
  const int wn = (wave >> 1) * 32;
  const int lr = tid >> 2;          // staging row 0..63
  const int kc = (tid & 3) * 8;     // staging k-chunk 0/8/16/24
  const int fl = lane & 15;         // fragment m/n index
  const int fq = lane >> 4;         // fragment quad (k group)

  floatx4 acc00 = {0,0,0,0}, acc01 = {0,0,0,0}, acc10 = {0,0,0,0}, acc11 = {0,0,0,0};
  const int gr = bm + lr;

  for (int k0 = 0; k0 < 256; k0 += 32) {
    short8 av, bv;
    if (gr < M) {
      const float* p = x + (size_t)gr * 256 + k0 + kc;
      #pragma unroll
      for (int j = 0; j < 8; ++j) av[j] = (short)f2b(p[j]);
    } else {
      #pragma unroll
      for (int j = 0; j < 8; ++j) av[j] = 0;
    }
    bv = *(const short8*)(Wt + (size_t)(bn + lr) * 256 + k0 + kc);

    __syncthreads();   // protect previous iteration's fragment reads
    *(short8*)&As[lr * LDA + kc] = av;
    *(short8*)&Bs[lr * LDA + kc] = bv;
    __syncthreads();

    short8 a0 = *(const short8*)&As[(wm + fl) * LDA + fq * 8];
    short8 a1 = *(const short8*)&As[(wm + 16 + fl) * LDA + fq * 8];
    short8 b0 = *(const short8*)&Bs[(wn + fl) * LDA + fq * 8];
    short8 b1 = *(const short8*)&Bs[(wn + 16 + fl) * LDA + fq * 8];
    acc00 = __builtin_amdgcn_mfma_f32_16x16x32_bf16(a0, b0, acc00, 0, 0, 0);
    acc01 = __builtin_amdgcn_mfma_f32_16x16x32_bf16(a0, b1, acc01, 0, 0, 0);
    acc10 = __builtin_amdgcn_mfma_f32_16x16x32_bf16(a1, b0, acc10, 0, 0, 0);
    acc11 = __builtin_amdgcn_mfma_f32_16x16x32_bf16(a1, b1, acc11, 0, 0, 0);
  }

  // C/D layout (m89-verified): col = lane&15, row = (lane>>4)*4 + reg
  const int r0 = bm + wm + fq * 4;
  const int c0 = bn + wn + fl;
  #pragma unroll
  for (int r = 0; r < 4; ++r) {
    int row = r0 + r;
    if (row < M) {
      xwb[(size_t)row * 256 + c0]      = f2b(acc00[r]);
      xwb[(size_t)row * 256 + c0 + 16] = f2b(acc01[r]);
    }
    int row2 = row + 16;
    if (row2 < M) {
      xwb[(size_t)row2 * 256 + c0]      = f2b(acc10[r]);
      xwb[(size_t)row2 * 256 + c0 + 16] = f2b(acc11[r]);
    }
  }
}

// ---- counting sort of edges by dst ----
__global__ void hist_kernel(const int* __restrict__ edst, int* __restrict__ deg, int E) {
  int e = blockIdx.x * 256 + threadIdx.x;
  if (e < E) atomicAdd(&deg[edst[e]], 1);
}

__global__ void scan_partial_kernel(const int* __restrict__ deg,
                                    int* __restrict__ partials, int M) {
  __shared__ int s[256];
  int t = threadIdx.x, i = blockIdx.x * 256 + t;
  s[t] = (i < M) ? deg[i] : 0;
  __syncthreads();
  for (int o = 128; o > 0; o >>= 1) {
    if (t < o) s[t] += s[t + o];
    __syncthreads();
  }
  if (t == 0) partials[blockIdx.x] = s[0];
}

__global__ void scan_top_kernel(int* __restrict__ partials, int nb) {
  __shared__ int s[256];
  int t = threadIdx.x;
  int v = (t < nb) ? partials[t] : 0;
  s[t] = v; __syncthreads();
  for (int o = 1; o < 256; o <<= 1) {
    int x = (t >= o) ? s[t - o] : 0;
    __syncthreads();
    s[t] += x;
    __syncthreads();
  }
  if (t < nb) partials[t] = s[t] - v;   // exclusive
}

__global__ void scan_final_kernel(const int* __restrict__ deg,
                                  const int* __restrict__ partials,
                                  int* __restrict__ offs, int* __restrict__ cursor,
                                  int M, int E) {
  __shared__ int s[256];
  int t = threadIdx.x, i = blockIdx.x * 256 + t;
  int v = (i < M) ? deg[i] : 0;
  s[t] = v; __syncthreads();
  for (int o = 1; o < 256; o <<= 1) {
    int x = (t >= o) ? s[t - o] : 0;
    __syncthreads();
    s[t] += x;
    __syncthreads();
  }
  int excl = s[t] - v + partials[blockIdx.x];
  if (i < M) { offs[i] = excl; cursor[i] = excl; }
  if (blockIdx.x == 0 && t == 0) offs[M] = E;
}

__global__ void scatter_kernel(const int* __restrict__ esrc, const int* __restrict__ edst,
                               const float* __restrict__ eval, int* __restrict__ cursor,
                               int* __restrict__ ssrc, float* __restrict__ sval, int E) {
  int e = blockIdx.x * 256 + threadIdx.x;
  if (e < E) {
    int d = edst[e];
    int p = atomicAdd(&cursor[d], 1);
    ssrc[p] = esrc[e];
    sval[p] = eval[e];
  }
}

// ---- gather: one wave per node, 4 channels/lane (float4 out) ----
__global__ __launch_bounds__(256) void gather_kernel(
    const unsigned short* __restrict__ xwb, const int* __restrict__ offs,
    const int* __restrict__ ssrc, const float* __restrict__ sval,
    const float* __restrict__ bias, float* __restrict__ out, int M)
{
  const int node = blockIdx.x * 4 + (threadIdx.x >> 6);
  const int lane = threadIdx.x & 63;
  if (node >= M) return;
  const int e0 = offs[node];
  const int e1 = offs[node + 1];
  const int c = lane * 4;

  float a0 = 0.f, a1 = 0.f, a2 = 0.f, a3 = 0.f;
  int e = e0;
  int sn = 0; float vn = 0.f;
  if (e < e1) { sn = ssrc[e]; vn = sval[e]; }
  while (e < e1) {
    const int s = sn; const float v = vn;
    ++e;
    if (e < e1) { sn = ssrc[e]; vn = sval[e]; }   // prefetch next edge
    const ushort4 u = *(const ushort4*)(xwb + (size_t)s * 256 + c);
    a0 += v * b2f(u.x);
    a1 += v * b2f(u.y);
    a2 += v * b2f(u.z);
    a3 += v * b2f(u.w);
  }
  const float4 bv = *(const float4*)(bias + c);
  float4 o; o.x = a0 + bv.x; o.y = a1 + bv.y; o.z = a2 + bv.z; o.w = a3 + bv.w;
  *(float4*)(out + (size_t)node * 256 + c) = o;
}

extern "C" void kernel_launch(void* const* d_in, const int* in_sizes, int n_in,
                              void* d_out, int out_size, void* d_ws, size_t ws_size,
                              hipStream_t stream) {
  const float* x    = (const float*)d_in[0];
  const float* W    = (const float*)d_in[1];
  const float* bias = (const float*)d_in[2];
  const int*   esrc = (const int*)d_in[3];
  const int*   edst = (const int*)d_in[4];
  const float* eval = (const float*)d_in[5];
  float* out = (float*)d_out;

  const int M = in_sizes[0] / 256;   // 50000 nodes
  const int E = in_sizes[3];         // 800000 edges

  // workspace carve-up (256B aligned)
  char* ws = (char*)d_ws;
  size_t off = 0;
  auto alloc = [&](size_t bytes) -> void* {
    void* p = ws + off;
    off += (bytes + 255) & ~(size_t)255;
    return p;
  };
  unsigned short* xwb = (unsigned short*)alloc((size_t)M * 256 * 2);
  unsigned short* Wt  = (unsigned short*)alloc(256 * 256 * 2);
  int*   deg      = (int*)alloc((size_t)M * 4);
  int*   offs     = (int*)alloc((size_t)(M + 1) * 4);
  int*   cursor   = (int*)alloc((size_t)M * 4);
  int*   partials = (int*)alloc(256 * 4);
  int*   ssrc     = (int*)alloc((size_t)E * 4);
  float* sval     = (float*)alloc((size_t)E * 4);

  hipMemsetAsync(deg, 0, (size_t)M * 4, stream);

  wt_kernel<<<256, 256, 0, stream>>>(W, Wt);
  dim3 ggrid((M + 63) / 64, 4);
  gemm_kernel<<<ggrid, 256, 0, stream>>>(x, Wt, xwb, M);

  const int nb = (M + 255) / 256;    // 196 <= 256
  hist_kernel<<<(E + 255) / 256, 256, 0, stream>>>(edst, deg, E);
  scan_partial_kernel<<<nb, 256, 0, stream>>>(deg, partials, M);
  scan_top_kernel<<<1, 256, 0, stream>>>(partials, nb);
  scan_final_kernel<<<nb, 256, 0, stream>>>(deg, partials, offs, cursor, M, E);
  scatter_kernel<<<(E + 255) / 256, 256, 0, stream>>>(esrc, edst, eval, cursor, ssrc, sval, E);

  gather_kernel<<<(M + 3) / 4, 256, 0, stream>>>(xwb, offs, ssrc, sval, bias, out, M);
}

// Round 2
// 240.883 us; speedup vs baseline: 1.2042x; 1.2042x over previous
//
#include <hip/hip_runtime.h>
#include <stdint.h>

typedef __attribute__((ext_vector_type(8))) short short8;
typedef __attribute__((ext_vector_type(4))) float floatx4;

#define CH 256

__device__ __forceinline__ unsigned short f2b(float f) {
  union { float f; uint32_t u; } v; v.f = f;
  uint32_t u = v.u;
  uint32_t r = u + 0x7FFFu + ((u >> 16) & 1u);   // round-to-nearest-even
  return (unsigned short)(r >> 16);
}
__device__ __forceinline__ float b2f(unsigned short h) {
  union { uint32_t u; float f; } v; v.u = ((uint32_t)h) << 16;
  return v.f;
}

__device__ __forceinline__ void async16(const void* g, void* l) {
  __builtin_amdgcn_global_load_lds(
      (const __attribute__((address_space(1))) unsigned int*)g,
      (__attribute__((address_space(3))) unsigned int*)l, 16, 0, 0);
}

// ===== K1: fused [x->bf16 convert | W transpose->bf16 | hist+rank] =====
__global__ __launch_bounds__(256) void pre_kernel(
    const float* __restrict__ x, const float* __restrict__ W,
    const int* __restrict__ edst,
    unsigned short* __restrict__ xb, unsigned short* __restrict__ Wt,
    int* __restrict__ deg, int* __restrict__ rank,
    int M, int E, int CVB)
{
  const int b = blockIdx.x, t = threadIdx.x;
  if (b < CVB) {
    const size_t total = (size_t)M * CH;
    size_t i = (size_t)b * 2048 + (size_t)t * 8;
    if (i + 8 <= total) {
      const float4* p = (const float4*)(x + i);
      float4 v0 = p[0], v1 = p[1];
      short8 o;
      o[0] = f2b(v0.x); o[1] = f2b(v0.y); o[2] = f2b(v0.z); o[3] = f2b(v0.w);
      o[4] = f2b(v1.x); o[5] = f2b(v1.y); o[6] = f2b(v1.z); o[7] = f2b(v1.w);
      *(short8*)(xb + i) = o;
    } else {
      for (size_t k = i; k < total; ++k) xb[k] = f2b(x[k]);
    }
  } else if (b < CVB + 256) {
    const int n = b - CVB;
    Wt[n * CH + t] = f2b(W[t * CH + n]);
  } else {
    const int e = (b - CVB - 256) * 256 + t;
    if (e < E) {
      const int d = edst[e];
      rank[e] = atomicAdd(&deg[d], 1);
    }
  }
}

// ===== scan chain: deg -> exclusive offs =====
__global__ void scan_partial_kernel(const int* __restrict__ deg,
                                    int* __restrict__ partials, int M) {
  __shared__ int s[256];
  int t = threadIdx.x, i = blockIdx.x * 256 + t;
  s[t] = (i < M) ? deg[i] : 0;
  __syncthreads();
  for (int o = 128; o > 0; o >>= 1) {
    if (t < o) s[t] += s[t + o];
    __syncthreads();
  }
  if (t == 0) partials[blockIdx.x] = s[0];
}

__global__ void scan_top_kernel(int* __restrict__ partials, int nb) {
  __shared__ int s[256];
  int t = threadIdx.x;
  int v = (t < nb) ? partials[t] : 0;
  s[t] = v; __syncthreads();
  for (int o = 1; o < 256; o <<= 1) {
    int x = (t >= o) ? s[t - o] : 0;
    __syncthreads();
    s[t] += x;
    __syncthreads();
  }
  if (t < nb) partials[t] = s[t] - v;   // exclusive
}

__global__ void scan_final_kernel(const int* __restrict__ deg,
                                  const int* __restrict__ partials,
                                  int* __restrict__ offs, int M, int E) {
  __shared__ int s[256];
  int t = threadIdx.x, i = blockIdx.x * 256 + t;
  int v = (i < M) ? deg[i] : 0;
  s[t] = v; __syncthreads();
  for (int o = 1; o < 256; o <<= 1) {
    int x = (t >= o) ? s[t - o] : 0;
    __syncthreads();
    s[t] += x;
    __syncthreads();
  }
  int excl = s[t] - v + partials[blockIdx.x];
  if (i < M) offs[i] = excl;
  if (blockIdx.x == 0 && t == 0) offs[M] = E;
}

// ===== K5: fused [128x128 MFMA GEMM (global_load_lds, XOR swizzle) | scatter] =====
__global__ __launch_bounds__(256) void mid_kernel(
    const unsigned short* __restrict__ xb, const unsigned short* __restrict__ Wt,
    unsigned short* __restrict__ xwb,
    const int* __restrict__ esrc, const int* __restrict__ edst,
    const float* __restrict__ eval, const int* __restrict__ offs,
    const int* __restrict__ rank, int2* __restrict__ se,
    int M, int E, int GB, int GBX)
{
  __shared__ unsigned short As[128 * 32];   // row-major, row stride 32 shorts (64B), NO pad
  __shared__ unsigned short Bs[128 * 32];

  if (blockIdx.x < GB) {
    const int bx = blockIdx.x % GBX;
    const int by = blockIdx.x / GBX;
    const int bm = bx * 128;
    const int bn = by * 128;
    const int t = threadIdx.x;
    const int w = t >> 6;
    const int l = t & 63;
    const int fl = l & 15;
    const int fq = l >> 4;
    const int wm = (w & 1) * 64;
    const int wn = (w >> 1) * 64;

    // staging geometry: 8 chunks of 16 rows; wave w stages chunks {2w, 2w+1}
    const int srow_in = l >> 2;                       // 0..15
    const int skc = ((l & 3) ^ ((l >> 3) & 3)) * 8;   // XOR-swizzled source k-chunk

    floatx4 acc[4][4];
    #pragma unroll
    for (int i = 0; i < 4; ++i)
      #pragma unroll
      for (int j = 0; j < 4; ++j) acc[i][j] = (floatx4){0.f, 0.f, 0.f, 0.f};

    for (int k0 = 0; k0 < CH; k0 += 32) {
      #pragma unroll
      for (int j = 0; j < 2; ++j) {
        const int chunk = w * 2 + j;
        const int row = chunk * 16 + srow_in;
        int gr = bm + row; if (gr > M - 1) gr = M - 1;   // clamp (junk rows unsaved)
        async16(&xb[(size_t)gr * CH + k0 + skc], &As[chunk * 512]);
        async16(&Wt[(size_t)(bn + row) * CH + k0 + skc], &Bs[chunk * 512]);
      }
      __syncthreads();

      short8 af[4], bf[4];
      #pragma unroll
      for (int mi = 0; mi < 4; ++mi) {
        const int r = wm + mi * 16 + fl;
        const int slot = fq ^ ((r >> 1) & 3);
        af[mi] = *(const short8*)&As[r * 32 + slot * 8];
      }
      #pragma unroll
      for (int ni = 0; ni < 4; ++ni) {
        const int r = wn + ni * 16 + fl;
        const int slot = fq ^ ((r >> 1) & 3);
        bf[ni] = *(const short8*)&Bs[r * 32 + slot * 8];
      }
      #pragma unroll
      for (int mi = 0; mi < 4; ++mi)
        #pragma unroll
        for (int ni = 0; ni < 4; ++ni)
          acc[mi][ni] = __builtin_amdgcn_mfma_f32_16x16x32_bf16(af[mi], bf[ni], acc[mi][ni], 0, 0, 0);
      __syncthreads();
    }

    // C/D layout: col = lane&15, row = (lane>>4)*4 + reg
    #pragma unroll
    for (int mi = 0; mi < 4; ++mi) {
      #pragma unroll
      for (int r = 0; r < 4; ++r) {
        const int m = bm + wm + mi * 16 + fq * 4 + r;
        if (m < M) {
          #pragma unroll
          for (int ni = 0; ni < 4; ++ni)
            xwb[(size_t)m * CH + bn + wn + ni * 16 + fl] = f2b(acc[mi][ni][r]);
        }
      }
    }
  } else {
    const int e = (blockIdx.x - GB) * 256 + threadIdx.x;
    if (e < E) {
      const int d = edst[e];
      const int p = offs[d] + rank[e];
      se[p] = make_int2(esrc[e], __float_as_int(eval[e]));
    }
  }
}

// ===== K6: gather, one wave/node, unroll-4 edges, 4 independent accumulators =====
__global__ __launch_bounds__(256) void gather_kernel(
    const unsigned short* __restrict__ xwb, const int* __restrict__ offs,
    const int2* __restrict__ se, const float* __restrict__ bias,
    float* __restrict__ out, int M)
{
  const int node = blockIdx.x * 4 + (threadIdx.x >> 6);
  const int lane = threadIdx.x & 63;
  if (node >= M) return;
  int e = offs[node];
  const int e1 = offs[node + 1];
  const int c = lane * 4;
  const float4 bv = *(const float4*)(bias + c);

  float4 a0 = {0,0,0,0}, a1 = {0,0,0,0}, a2 = {0,0,0,0}, a3 = {0,0,0,0};

  for (; e + 4 <= e1; e += 4) {
    const int2 r0 = se[e], r1 = se[e + 1], r2 = se[e + 2], r3 = se[e + 3];
    const ushort4 u0 = *(const ushort4*)(xwb + (size_t)r0.x * CH + c);
    const ushort4 u1 = *(const ushort4*)(xwb + (size_t)r1.x * CH + c);
    const ushort4 u2 = *(const ushort4*)(xwb + (size_t)r2.x * CH + c);
    const ushort4 u3 = *(const ushort4*)(xwb + (size_t)r3.x * CH + c);
    const float v0 = __int_as_float(r0.y), v1 = __int_as_float(r1.y);
    const float v2 = __int_as_float(r2.y), v3 = __int_as_float(r3.y);
    a0.x += v0 * b2f(u0.x); a0.y += v0 * b2f(u0.y); a0.z += v0 * b2f(u0.z); a0.w += v0 * b2f(u0.w);
    a1.x += v1 * b2f(u1.x); a1.y += v1 * b2f(u1.y); a1.z += v1 * b2f(u1.z); a1.w += v1 * b2f(u1.w);
    a2.x += v2 * b2f(u2.x); a2.y += v2 * b2f(u2.y); a2.z += v2 * b2f(u2.z); a2.w += v2 * b2f(u2.w);
    a3.x += v3 * b2f(u3.x); a3.y += v3 * b2f(u3.y); a3.z += v3 * b2f(u3.z); a3.w += v3 * b2f(u3.w);
  }
  for (; e < e1; ++e) {
    const int2 r = se[e];
    const ushort4 u = *(const ushort4*)(xwb + (size_t)r.x * CH + c);
    const float v = __int_as_float(r.y);
    a0.x += v * b2f(u.x); a0.y += v * b2f(u.y); a0.z += v * b2f(u.z); a0.w += v * b2f(u.w);
  }

  float4 o;
  o.x = a0.x + a1.x + a2.x + a3.x + bv.x;
  o.y = a0.y + a1.y + a2.y + a3.y + bv.y;
  o.z = a0.z + a1.z + a2.z + a3.z + bv.z;
  o.w = a0.w + a1.w + a2.w + a3.w + bv.w;
  *(float4*)(out + (size_t)node * CH + c) = o;
}

extern "C" void kernel_launch(void* const* d_in, const int* in_sizes, int n_in,
                              void* d_out, int out_size, void* d_ws, size_t ws_size,
                              hipStream_t stream) {
  const float* x    = (const float*)d_in[0];
  const float* W    = (const float*)d_in[1];
  const float* bias = (const float*)d_in[2];
  const int*   esrc = (const int*)d_in[3];
  const int*   edst = (const int*)d_in[4];
  const float* eval = (const float*)d_in[5];
  float* out = (float*)d_out;

  const int M = in_sizes[0] / CH;    // 50000 nodes
  const int E = in_sizes[3];         // 800000 edges

  char* ws = (char*)d_ws;
  size_t off = 0;
  auto alloc = [&](size_t bytes) -> void* {
    void* p = ws + off;
    off += (bytes + 255) & ~(size_t)255;
    return p;
  };
  unsigned short* xb  = (unsigned short*)alloc((size_t)M * CH * 2);
  unsigned short* xwb = (unsigned short*)alloc((size_t)M * CH * 2);
  unsigned short* Wt  = (unsigned short*)alloc(CH * CH * 2);
  int*   deg      = (int*)alloc((size_t)M * 4);
  int*   offs     = (int*)alloc((size_t)(M + 1) * 4);
  int*   rank     = (int*)alloc((size_t)E * 4);
  int*   partials = (int*)alloc(256 * 4);
  int2*  se       = (int2*)alloc((size_t)E * 8);

  hipMemsetAsync(deg, 0, (size_t)M * 4, stream);

  const int CVB = (int)(((size_t)M * CH + 2047) / 2048);   // convert blocks
  const int HB  = (E + 255) / 256;                          // hist blocks
  pre_kernel<<<CVB + 256 + HB, 256, 0, stream>>>(x, W, edst, xb, Wt, deg, rank, M, E, CVB);

  const int nb = (M + 255) / 256;    // 196 <= 256
  scan_partial_kernel<<<nb, 256, 0, stream>>>(deg, partials, M);
  scan_top_kernel<<<1, 256, 0, stream>>>(partials, nb);
  scan_final_kernel<<<nb, 256, 0, stream>>>(deg, partials, offs, M, E);

  const int GBX = (M + 127) / 128;           // 391
  const int GB  = GBX * (CH / 128);          // 782 gemm blocks
  mid_kernel<<<GB + HB, 256, 0, stream>>>(xb, Wt, xwb, esrc, edst, eval,
                                          offs, rank, se, M, E, GB, GBX);

  gather_kernel<<<(M + 3) / 4, 256, 0, stream>>>(xwb, offs, se, bias, out, M);
}